// Round 2
// baseline (941.893 us; speedup 1.0000x reference)
//
#include <hip/hip_runtime.h>
#include <math.h>

#define BSZ 4
#define CKC 64
#define HWP 1024
#define NMEM 16384
#define CVC 256
#define PT 16        // pixels per block
#define NT 128       // memory entries per LDS tile (stage 1)
#define NSPLIT 8     // n-chunks (blocks) per pixel-group
#define CHUNK (NMEM / NSPLIT)   // 2048

// workspace layout (in floats)
#define WS_BQ_OFF    0
#define WS_BQ_SZ     (BSZ * 128 * HWP)
#define WS_BSQ_OFF   (WS_BQ_OFF + WS_BQ_SZ)
#define WS_BSQ_SZ    (BSZ * HWP)
#define WS_PRE_OFF   (WS_BSQ_OFF + WS_BSQ_SZ)
#define WS_PRE_SZ    (BSZ * HWP)
#define WS_PARTV_OFF (WS_PRE_OFF + WS_PRE_SZ)
#define WS_PARTV_SZ  (BSZ * HWP * NSPLIT * 32)
#define WS_PARTI_OFF (WS_PARTV_OFF + WS_PARTV_SZ)
#define WS_PARTI_SZ  (BSZ * HWP * NSPLIT * 32)
#define WS_VT_OFF    (WS_PARTI_OFF + WS_PARTI_SZ)
#define WS_VT_SZ     (BSZ * NMEM * CVC)
#define WS_TOTAL_FLOATS (WS_VT_OFF + WS_VT_SZ)

// ---------------------------------------------------------------------------
// Prep: Bq rows 0..63 = 2*qk*qe ("f"), rows 64..127 = -qe ("g");
// bsq[p] = sum_c qe*qk^2 ; prelogit[p] = b + W_lm*lm + W1.lpf + W2.pf - W3.lmv
// ---------------------------------------------------------------------------
__global__ __launch_bounds__(256) void prep_kernel(
    const float* __restrict__ qk, const float* __restrict__ qe,
    const float* __restrict__ pf, const float* __restrict__ lm,
    const float* __restrict__ lpf, const float* __restrict__ lmv,
    const float* __restrict__ W, const float* __restrict__ bu,
    float* __restrict__ Bq, float* __restrict__ bsq, float* __restrict__ prelog)
{
    __shared__ float red[16][17];
    const int t  = threadIdx.x;
    const int b  = blockIdx.x >> 6;
    const int p0 = (blockIdx.x & 63) << 4;
    const int pp = t & 15;
    const int cg = t >> 4;
    const int p  = p0 + pp;

    const float* qkb = qk + (size_t)b * CKC * HWP;
    const float* qeb = qe + (size_t)b * CKC * HWP;
    float* Bqb = Bq + (size_t)b * 128 * HWP;

    float bs = 0.f;
    #pragma unroll
    for (int i = 0; i < 4; ++i) {
        const int cidx = (cg << 2) + i;
        const float k_ = qkb[cidx * HWP + p];
        const float e_ = qeb[cidx * HWP + p];
        Bqb[cidx * HWP + p]        = 2.f * k_ * e_;
        Bqb[(64 + cidx) * HWP + p] = -e_;
        bs += e_ * k_ * k_;
    }
    red[cg][pp] = bs;
    __syncthreads();
    if (t < 16) {
        float s = 0.f;
        #pragma unroll
        for (int g2 = 0; g2 < 16; ++g2) s += red[g2][t];
        bsq[b * HWP + p0 + t] = s;
    }
    const float* lpfb = lpf + (size_t)b * CVC * HWP;
    const float* pfb  = pf  + (size_t)b * CVC * HWP;
    const float* lmvb = lmv + (size_t)b * CVC * HWP;
    float lg = 0.f;
    #pragma unroll
    for (int i = 0; i < 16; ++i) {
        const int cidx = (cg << 4) + i;
        lg += W[cidx]       * lpfb[cidx * HWP + p];
        lg += W[256 + cidx] * pfb[cidx * HWP + p];
        lg -= W[513 + cidx] * lmvb[cidx * HWP + p];
    }
    __syncthreads();
    red[cg][pp] = lg;
    __syncthreads();
    if (t < 16) {
        float s = bu[0] + W[512] * lm[b * HWP + p0 + t];
        #pragma unroll
        for (int g2 = 0; g2 < 16; ++g2) s += red[g2][t];
        prelog[b * HWP + p0 + t] = s;
    }
}

// ---------------------------------------------------------------------------
// Transpose mem_msk_value [b][c][n] -> VT [b][n][c]
// ---------------------------------------------------------------------------
__global__ __launch_bounds__(256) void transpose_v(const float* __restrict__ V,
                                                   float* __restrict__ VT)
{
    __shared__ float tile[32][33];
    const int b  = blockIdx.z;
    const int n0 = blockIdx.x << 5;
    const int c0 = blockIdx.y << 5;
    const int tx = threadIdx.x, ty = threadIdx.y;  // 32 x 8
    const float* Vb  = V  + (size_t)b * CVC * NMEM;
    float*       VTb = VT + (size_t)b * NMEM * CVC;
    #pragma unroll
    for (int i = 0; i < 32; i += 8)
        tile[ty + i][tx] = Vb[(size_t)(c0 + ty + i) * NMEM + n0 + tx];
    __syncthreads();
    #pragma unroll
    for (int i = 0; i < 32; i += 8)
        VTb[(size_t)(n0 + ty + i) * CVC + c0 + tx] = tile[tx][ty + i];
}

// ---------------------------------------------------------------------------
// Stage 1: sim GEMM over an n-chunk of 2048 + streaming per-chunk top-32.
// grid = BSZ * 64 * NSPLIT blocks, 256 threads.
// Thread tile 4n x 2p: tn = t&31 (n-quads), tp = t>>5 (p-pairs).
// ---------------------------------------------------------------------------
__global__ __launch_bounds__(256) void sim_topk_kernel(
    const float* __restrict__ mk, const float* __restrict__ shr,
    const float* __restrict__ valid, const float* __restrict__ Bq,
    const float* __restrict__ bsq,
    float* __restrict__ partV, float* __restrict__ partI)
{
    __shared__ float fS[64][16];
    __shared__ float gS[64][16];
    __shared__ float mkS[64][NT];
    __shared__ float shrS[NT];
    __shared__ float penS[NT];
    __shared__ float bsqS[PT];
    __shared__ float heapV[PT][32];
    __shared__ int   heapI[PT][32];
    __shared__ float minV[PT];
    __shared__ int   minPos[PT];
    __shared__ float qV[PT][32];
    __shared__ int   qI[PT][32];
    __shared__ int   qCnt[PT];
    __shared__ int   pendAny;

    const int t     = threadIdx.x;
    const int b     = blockIdx.x >> 9;             // /(64*NSPLIT)
    const int pg    = (blockIdx.x >> 3) & 63;
    const int ns    = blockIdx.x & 7;
    const int p0    = pg << 4;
    const int nbase = ns * CHUNK;
    const int tn    = t & 31;
    const int tp    = t >> 5;

    const float* Bqb = Bq + (size_t)b * 128 * HWP;
    for (int idx = t; idx < 64 * PT; idx += 256) {
        const int c = idx >> 4, pp = idx & 15;
        fS[c][pp] = Bqb[c * HWP + p0 + pp];
        gS[c][pp] = Bqb[(64 + c) * HWP + p0 + pp];
    }
    if (t < PT) {
        bsqS[t] = bsq[b * HWP + p0 + t];
        qCnt[t] = 0;
    }
    if (t == 0) pendAny = 0;

    const float* mkb  = mk    + (size_t)b * CKC * NMEM;
    const float* shrb = shr   + (size_t)b * NMEM;
    const float* vlb  = valid + (size_t)b * NMEM;

    for (int ntile = 0; ntile < CHUNK / NT; ++ntile) {
        const int nstart = nbase + ntile * NT;
        if (t < NT) {
            shrS[t] = shrb[nstart + t] * 0.125f;            // 1/sqrt(64)
            penS[t] = (1.f - vlb[nstart + t]) * -60000.f;
        }
        #pragma unroll
        for (int k = 0; k < 8; ++k) {
            const int idx = t + (k << 8);                   // 0..2047 float4s
            const int row = idx >> 5;
            const int c4  = (idx & 31) << 2;
            *(float4*)&mkS[row][c4] =
                *(const float4*)&mkb[(size_t)row * NMEM + nstart + c4];
        }
        __syncthreads();

        // ---- sim GEMM ----
        float acc[4][2];
        #pragma unroll
        for (int i = 0; i < 4; ++i) { acc[i][0] = 0.f; acc[i][1] = 0.f; }

        #pragma unroll 8
        for (int cc = 0; cc < 64; ++cc) {
            const float4 a4 = *(const float4*)&mkS[cc][tn << 2];
            const float2 f2 = *(const float2*)&fS[cc][tp << 1];
            const float2 g2 = *(const float2*)&gS[cc][tp << 1];
            const float m[4]  = {a4.x, a4.y, a4.z, a4.w};
            #pragma unroll
            for (int i = 0; i < 4; ++i) {
                const float mv = m[i];
                const float m2 = mv * mv;
                acc[i][0] = fmaf(mv, f2.x, fmaf(m2, g2.x, acc[i][0]));
                acc[i][1] = fmaf(mv, f2.y, fmaf(m2, g2.y, acc[i][1]));
            }
        }

        float simv[4][2];
        #pragma unroll
        for (int i = 0; i < 4; ++i) {
            const float sh = shrS[(tn << 2) + i];
            const float pe = penS[(tn << 2) + i];
            #pragma unroll
            for (int j = 0; j < 2; ++j)
                simv[i][j] = fmaf(acc[i][j] - bsqS[(tp << 1) + j], sh, pe);
        }

        // ---- streaming top-32 ----
        unsigned pending = 0xFFu;                            // 4n x 2p bits
        if (ntile == 0) {
            if (tn < 8) {                                    // n 0..31 warm-up
                #pragma unroll
                for (int i = 0; i < 4; ++i)
                    #pragma unroll
                    for (int j = 0; j < 2; ++j) {
                        heapV[(tp << 1) + j][(tn << 2) + i] = simv[i][j];
                        heapI[(tp << 1) + j][(tn << 2) + i] = nbase + (tn << 2) + i;
                    }
                pending = 0;
            }
            __syncthreads();
            if (t < PT) {
                float mv = heapV[t][0]; int mp = 0;
                #pragma unroll
                for (int s = 1; s < 32; ++s) {
                    const float v = heapV[t][s];
                    if (v < mv) { mv = v; mp = s; }
                }
                minV[t] = mv; minPos[t] = mp;
            }
            __syncthreads();
        }

        while (true) {
            if (t == 0) pendAny = 0;
            if (t < PT) qCnt[t] = 0;
            __syncthreads();
            if (pending) {
                #pragma unroll
                for (int j = 0; j < 2; ++j) {
                    const int p = (tp << 1) + j;
                    const float mv = minV[p];
                    #pragma unroll
                    for (int i = 0; i < 4; ++i) {
                        const unsigned bitm = 1u << ((j << 2) + i);
                        if (pending & bitm) {
                            const float v = simv[i][j];
                            if (v > mv) {
                                const int slot = atomicAdd(&qCnt[p], 1);
                                if (slot < 32) {
                                    qV[p][slot] = v;
                                    qI[p][slot] = nstart + (tn << 2) + i;
                                    pending &= ~bitm;
                                }
                            } else pending &= ~bitm;
                        }
                    }
                }
                if (pending) pendAny = 1;
            }
            __syncthreads();
            if (t < PT) {
                const int p = t;
                int cnt = qCnt[p]; if (cnt > 32) cnt = 32;
                if (cnt) {
                    float mv = minV[p]; int mp = minPos[p];
                    for (int s = 0; s < cnt; ++s) {
                        const float v = qV[p][s];
                        if (v > mv) {
                            heapV[p][mp] = v;
                            heapI[p][mp] = qI[p][s];
                            mv = heapV[p][0]; mp = 0;
                            for (int s2 = 1; s2 < 32; ++s2) {
                                const float v2 = heapV[p][s2];
                                if (v2 < mv) { mv = v2; mp = s2; }
                            }
                        }
                    }
                    minV[p] = mv; minPos[p] = mp;
                }
            }
            __syncthreads();
            const int again = pendAny;
            __syncthreads();
            if (!again) break;
        }
    }

    // ---- write per-chunk top-32 candidates ----
    #pragma unroll
    for (int idx = t; idx < PT * 32; idx += 256) {
        const int p = idx >> 5, s = idx & 31;
        const size_t gp = (size_t)b * HWP + p0 + p;
        partV[gp * (NSPLIT * 32) + ns * 32 + s] = heapV[p][s];
        partI[gp * (NSPLIT * 32) + ns * 32 + s] = (float)heapI[p][s];
    }
}

// ---------------------------------------------------------------------------
// Stage 2: merge NSPLIT*32 candidates -> exact top-30 softmax -> gather+blend.
// grid = BSZ * 64 blocks, 256 threads.
// ---------------------------------------------------------------------------
__global__ __launch_bounds__(256) void merge_kernel(
    const float* __restrict__ partV, const float* __restrict__ partI,
    const float* __restrict__ Vv, const float* __restrict__ lmv,
    const float* __restrict__ prelog, const float* __restrict__ W,
    float* __restrict__ out, int use_vt)
{
    __shared__ float candV[PT][NSPLIT * 32];
    __shared__ int   candI[PT][NSPLIT * 32];
    __shared__ float heapV[PT][32];
    __shared__ int   heapI[PT][32];
    __shared__ float probS[PT][32];
    __shared__ float prelS[PT];
    __shared__ float partS[4][PT];
    __shared__ float upS[PT];

    const int t  = threadIdx.x;
    const int b  = blockIdx.x >> 6;
    const int pg = blockIdx.x & 63;
    const int p0 = pg << 4;
    const int NC = NSPLIT * 32;                      // 256 candidates/pixel

    for (int idx = t; idx < PT * NC; idx += 256) {
        const int p = idx >> 8, s = idx & (NC - 1);
        const size_t gp = (size_t)b * HWP + p0 + p;
        candV[p][s] = partV[gp * NC + s];
        candI[p][s] = (int)partI[gp * NC + s];
    }
    if (t < PT) prelS[t] = prelog[b * HWP + p0 + t];
    __syncthreads();

    if (t < PT) {
        const int p = t;
        // exact top-32 of 256 (union of chunk top-32s superset of global top-32)
        float mv = candV[p][0]; int mp = 0;
        #pragma unroll
        for (int s = 0; s < 32; ++s) {
            heapV[p][s] = candV[p][s];
            heapI[p][s] = candI[p][s];
            if (candV[p][s] < mv) { mv = candV[p][s]; mp = s; }
        }
        for (int s = 32; s < NC; ++s) {
            const float v = candV[p][s];
            if (v > mv) {
                heapV[p][mp] = v;
                heapI[p][mp] = candI[p][s];
                mv = heapV[p][0]; mp = 0;
                for (int s2 = 1; s2 < 32; ++s2) {
                    const float v2 = heapV[p][s2];
                    if (v2 < mv) { mv = v2; mp = s2; }
                }
            }
        }
        // softmax over top-30 (exclude the 2 smallest of the 32)
        float mx = heapV[p][0];
        #pragma unroll
        for (int s = 1; s < 32; ++s) mx = fmaxf(mx, heapV[p][s]);
        float m1v = heapV[p][0]; int m1 = 0;
        #pragma unroll
        for (int s = 1; s < 32; ++s) { const float v = heapV[p][s]; if (v < m1v) { m1v = v; m1 = s; } }
        float m2v = 3.0e38f; int m2 = -1;
        #pragma unroll
        for (int s = 0; s < 32; ++s) {
            if (s != m1) { const float v = heapV[p][s]; if (v < m2v) { m2v = v; m2 = s; } }
        }
        float sum = 0.f;
        #pragma unroll
        for (int s = 0; s < 32; ++s) {
            const float e = (s == m1 || s == m2) ? 0.f : expf(heapV[p][s] - mx);
            probS[p][s] = e; sum += e;
        }
        const float inv = 1.f / sum;
        #pragma unroll
        for (int s = 0; s < 32; ++s) probS[p][s] *= inv;
    }
    __syncthreads();

    // ---- gather visual (t = channel), logit reduce, blend, store ----
    const int c  = t;
    const int ln = t & 63;
    const int wv = t >> 6;
    float vis[PT];
    const float* Vb = Vv + (use_vt ? (size_t)b * NMEM * CVC : (size_t)b * CVC * NMEM);
    #pragma unroll
    for (int p = 0; p < PT; ++p) {
        float a = 0.f;
        for (int s = 0; s < 32; ++s) {
            const float pr = probS[p][s];           // wave-uniform
            if (pr != 0.f) {
                const int idx = heapI[p][s];
                const float v = use_vt ? Vb[(size_t)idx * CVC + c]
                                       : Vb[(size_t)c * NMEM + idx];
                a = fmaf(pr, v, a);
            }
        }
        vis[p] = a;
    }
    const float w3 = W[513 + c];
    #pragma unroll
    for (int p = 0; p < PT; ++p) {
        float v = w3 * vis[p];
        #pragma unroll
        for (int off = 32; off > 0; off >>= 1) v += __shfl_xor(v, off, 64);
        if (ln == 0) partS[wv][p] = v;
    }
    __syncthreads();
    if (t < PT) {
        const float lg = prelS[t] + partS[0][t] + partS[1][t] + partS[2][t] + partS[3][t];
        upS[t] = 1.f / (1.f + expf(-lg));
    }
    __syncthreads();
    const float* lmvp = lmv + ((size_t)b * CVC + c) * HWP + p0;
    float*       outp = out + ((size_t)b * CVC + c) * HWP + p0;
    #pragma unroll
    for (int p = 0; p < PT; ++p) {
        const float u = upS[p];
        outp[p] = vis[p] * u + lmvp[p] * (1.f - u);
    }
}

// ---------------------------------------------------------------------------
extern "C" void kernel_launch(void* const* d_in, const int* in_sizes, int n_in,
                              void* d_out, int out_size, void* d_ws, size_t ws_size,
                              hipStream_t stream)
{
    const float* qk  = (const float*)d_in[0];
    const float* qe  = (const float*)d_in[1];
    const float* pf  = (const float*)d_in[2];
    const float* lm  = (const float*)d_in[4];
    const float* lpf = (const float*)d_in[5];
    const float* lmv = (const float*)d_in[6];
    const float* mk  = (const float*)d_in[7];
    const float* shr = (const float*)d_in[8];
    const float* Vv  = (const float*)d_in[9];
    const float* vld = (const float*)d_in[10];
    const float* W   = (const float*)d_in[12];
    const float* bu  = (const float*)d_in[13];
    float* out = (float*)d_out;
    float* ws  = (float*)d_ws;

    float* Bq     = ws + WS_BQ_OFF;
    float* bsq    = ws + WS_BSQ_OFF;
    float* prelog = ws + WS_PRE_OFF;
    float* partV  = ws + WS_PARTV_OFF;
    float* partI  = ws + WS_PARTI_OFF;
    float* VT     = ws + WS_VT_OFF;
    const int use_vt = (ws_size >= (size_t)WS_TOTAL_FLOATS * sizeof(float)) ? 1 : 0;

    prep_kernel<<<BSZ * 64, 256, 0, stream>>>(qk, qe, pf, lm, lpf, lmv, W, bu,
                                              Bq, bsq, prelog);
    if (use_vt)
        transpose_v<<<dim3(NMEM / 32, CVC / 32, BSZ), dim3(32, 8), 0, stream>>>(Vv, VT);
    sim_topk_kernel<<<BSZ * 64 * NSPLIT, 256, 0, stream>>>(mk, shr, vld, Bq, bsq,
                                                           partV, partI);
    merge_kernel<<<BSZ * 64, 256, 0, stream>>>(partV, partI, use_vt ? VT : Vv,
                                               lmv, prelog, W, out, use_vt);
}

// Round 3
// 800.324 us; speedup vs baseline: 1.1769x; 1.1769x over previous
//
#include <hip/hip_runtime.h>
#include <math.h>

#define BSZ 4
#define CKC 64
#define HWP 1024
#define NMEM 16384
#define CVC 256
#define PT 32        // pixels per block (stage 1)
#define NT 128       // memory entries per LDS tile (stage 1)
#define NSPLIT 4     // n-chunks per pixel-group
#define CHUNK (NMEM / NSPLIT)   // 4096
#define NC (NSPLIT * 32)        // 128 merge candidates per pixel
#define PT2 16       // pixels per block (merge)

// workspace layout (in floats)
#define WS_BQ_OFF    0
#define WS_BQ_SZ     (BSZ * 128 * HWP)
#define WS_BSQ_OFF   (WS_BQ_OFF + WS_BQ_SZ)
#define WS_BSQ_SZ    (BSZ * HWP)
#define WS_PRE_OFF   (WS_BSQ_OFF + WS_BSQ_SZ)
#define WS_PRE_SZ    (BSZ * HWP)
#define WS_PARTV_OFF (WS_PRE_OFF + WS_PRE_SZ)
#define WS_PARTV_SZ  (BSZ * HWP * NC)
#define WS_PARTI_OFF (WS_PARTV_OFF + WS_PARTV_SZ)
#define WS_PARTI_SZ  (BSZ * HWP * NC)
#define WS_VT_OFF    (WS_PARTI_OFF + WS_PARTI_SZ)
#define WS_VT_SZ     (BSZ * NMEM * CVC)
#define WS_TOTAL_FLOATS (WS_VT_OFF + WS_VT_SZ)

// ---------------------------------------------------------------------------
// Prep: Bq rows 0..63 = 2*qk*qe ("f"), rows 64..127 = -qe ("g");
// bsq[p] = sum_c qe*qk^2 ; prelogit[p] = b + W_lm*lm + W1.lpf + W2.pf - W3.lmv
// ---------------------------------------------------------------------------
__global__ __launch_bounds__(256) void prep_kernel(
    const float* __restrict__ qk, const float* __restrict__ qe,
    const float* __restrict__ pf, const float* __restrict__ lm,
    const float* __restrict__ lpf, const float* __restrict__ lmv,
    const float* __restrict__ W, const float* __restrict__ bu,
    float* __restrict__ Bq, float* __restrict__ bsq, float* __restrict__ prelog)
{
    __shared__ float red[16][17];
    const int t  = threadIdx.x;
    const int b  = blockIdx.x >> 6;
    const int p0 = (blockIdx.x & 63) << 4;
    const int pp = t & 15;
    const int cg = t >> 4;
    const int p  = p0 + pp;

    const float* qkb = qk + (size_t)b * CKC * HWP;
    const float* qeb = qe + (size_t)b * CKC * HWP;
    float* Bqb = Bq + (size_t)b * 128 * HWP;

    float bs = 0.f;
    #pragma unroll
    for (int i = 0; i < 4; ++i) {
        const int cidx = (cg << 2) + i;
        const float k_ = qkb[cidx * HWP + p];
        const float e_ = qeb[cidx * HWP + p];
        Bqb[cidx * HWP + p]        = 2.f * k_ * e_;
        Bqb[(64 + cidx) * HWP + p] = -e_;
        bs += e_ * k_ * k_;
    }
    red[cg][pp] = bs;
    __syncthreads();
    if (t < 16) {
        float s = 0.f;
        #pragma unroll
        for (int g2 = 0; g2 < 16; ++g2) s += red[g2][t];
        bsq[b * HWP + p0 + t] = s;
    }
    const float* lpfb = lpf + (size_t)b * CVC * HWP;
    const float* pfb  = pf  + (size_t)b * CVC * HWP;
    const float* lmvb = lmv + (size_t)b * CVC * HWP;
    float lg = 0.f;
    #pragma unroll
    for (int i = 0; i < 16; ++i) {
        const int cidx = (cg << 4) + i;
        lg += W[cidx]       * lpfb[cidx * HWP + p];
        lg += W[256 + cidx] * pfb[cidx * HWP + p];
        lg -= W[513 + cidx] * lmvb[cidx * HWP + p];
    }
    __syncthreads();
    red[cg][pp] = lg;
    __syncthreads();
    if (t < 16) {
        float s = bu[0] + W[512] * lm[b * HWP + p0 + t];
        #pragma unroll
        for (int g2 = 0; g2 < 16; ++g2) s += red[g2][t];
        prelog[b * HWP + p0 + t] = s;
    }
}

// ---------------------------------------------------------------------------
// Transpose mem_msk_value [b][c][n] -> VT [b][n][c]
// ---------------------------------------------------------------------------
__global__ __launch_bounds__(256) void transpose_v(const float* __restrict__ V,
                                                   float* __restrict__ VT)
{
    __shared__ float tile[32][33];
    const int b  = blockIdx.z;
    const int n0 = blockIdx.x << 5;
    const int c0 = blockIdx.y << 5;
    const int tx = threadIdx.x, ty = threadIdx.y;  // 32 x 8
    const float* Vb  = V  + (size_t)b * CVC * NMEM;
    float*       VTb = VT + (size_t)b * NMEM * CVC;
    #pragma unroll
    for (int i = 0; i < 32; i += 8)
        tile[ty + i][tx] = Vb[(size_t)(c0 + ty + i) * NMEM + n0 + tx];
    __syncthreads();
    #pragma unroll
    for (int i = 0; i < 32; i += 8)
        VTb[(size_t)(n0 + ty + i) * CVC + c0 + tx] = tile[tx][ty + i];
}

// ---------------------------------------------------------------------------
// Stage 1: sim GEMM over an n-chunk of 4096 + streaming top-32 (binary heap).
// grid = BSZ * (HWP/PT) * NSPLIT = 512 blocks, 256 threads.
// Thread tile 4n x 4p: tn = t&31 (n-quads, 32 groups), tp = t>>5 (p-quads, 8).
// Heaps are 1-indexed min-heaps: heapV[p][1..32], root = current 32nd-best.
// ---------------------------------------------------------------------------
__global__ __launch_bounds__(256) void sim_topk_kernel(
    const float* __restrict__ mk, const float* __restrict__ shr,
    const float* __restrict__ valid, const float* __restrict__ Bq,
    const float* __restrict__ bsq,
    float* __restrict__ partV, float* __restrict__ partI)
{
    __shared__ float mkS[64][NT];
    __shared__ float fS[64][PT];
    __shared__ float gS[64][PT];
    __shared__ float heapV[PT][34];
    __shared__ int   heapI[PT][34];
    __shared__ float qV[PT][33];
    __shared__ int   qI[PT][33];
    __shared__ float shrS[NT];
    __shared__ float penS[NT];
    __shared__ float bsqS[PT];
    __shared__ int   qCnt[PT];
    __shared__ int   pendAny;

    const int t     = threadIdx.x;
    const int b     = blockIdx.x >> 7;             // /(32*NSPLIT)
    const int pg    = (blockIdx.x >> 2) & 31;
    const int ns    = blockIdx.x & 3;
    const int p0    = pg << 5;                     // 32 px per block
    const int nbase = ns * CHUNK;
    const int tn    = t & 31;
    const int tp    = t >> 5;

    const float* Bqb = Bq + (size_t)b * 128 * HWP;
    for (int idx = t; idx < 64 * PT; idx += 256) {
        const int c = idx >> 5, pp = idx & 31;
        fS[c][pp] = Bqb[c * HWP + p0 + pp];
        gS[c][pp] = Bqb[(64 + c) * HWP + p0 + pp];
    }
    if (t < PT) {
        bsqS[t] = bsq[b * HWP + p0 + t];
        qCnt[t] = 0;
    }
    if (t == 0) pendAny = 0;

    const float* mkb  = mk    + (size_t)b * CKC * NMEM;
    const float* shrb = shr   + (size_t)b * NMEM;
    const float* vlb  = valid + (size_t)b * NMEM;

    for (int ntile = 0; ntile < CHUNK / NT; ++ntile) {
        const int nstart = nbase + ntile * NT;
        if (t < NT) {
            shrS[t] = shrb[nstart + t] * 0.125f;            // 1/sqrt(64)
            penS[t] = (1.f - vlb[nstart + t]) * -60000.f;
        }
        #pragma unroll
        for (int k = 0; k < 8; ++k) {
            const int idx = t + (k << 8);                   // 0..2047 float4s
            const int row = idx >> 5;
            const int c4  = (idx & 31) << 2;
            *(float4*)&mkS[row][c4] =
                *(const float4*)&mkb[(size_t)row * NMEM + nstart + c4];
        }
        __syncthreads();

        // ---- sim GEMM: 4n x 4p per thread ----
        float acc[4][4];
        #pragma unroll
        for (int i = 0; i < 4; ++i)
            #pragma unroll
            for (int j = 0; j < 4; ++j) acc[i][j] = 0.f;

        #pragma unroll 8
        for (int cc = 0; cc < 64; ++cc) {
            const float4 a4 = *(const float4*)&mkS[cc][tn << 2];
            const float4 f4 = *(const float4*)&fS[cc][tp << 2];
            const float4 g4 = *(const float4*)&gS[cc][tp << 2];
            const float m[4]  = {a4.x, a4.y, a4.z, a4.w};
            const float ff[4] = {f4.x, f4.y, f4.z, f4.w};
            const float gg[4] = {g4.x, g4.y, g4.z, g4.w};
            #pragma unroll
            for (int i = 0; i < 4; ++i) {
                const float mv = m[i];
                #pragma unroll
                for (int j = 0; j < 4; ++j) {
                    const float t1 = fmaf(mv, gg[j], ff[j]);   // f + m*g
                    acc[i][j] = fmaf(mv, t1, acc[i][j]);       // += m*(f+m*g)
                }
            }
        }

        float simv[4][4];
        #pragma unroll
        for (int i = 0; i < 4; ++i) {
            const float sh = shrS[(tn << 2) + i];
            const float pe = penS[(tn << 2) + i];
            #pragma unroll
            for (int j = 0; j < 4; ++j)
                simv[i][j] = fmaf(acc[i][j] - bsqS[(tp << 2) + j], sh, pe);
        }

        // ---- streaming top-32 via per-pixel binary min-heap ----
        unsigned pending = 0xFFFFu;
        if (ntile == 0) {
            // warm-up: n-local 0..31 (tn<8) seed heap slots 1..32 directly
            if (tn < 8) {
                #pragma unroll
                for (int j = 0; j < 4; ++j) {
                    const int p = (tp << 2) + j;
                    #pragma unroll
                    for (int i = 0; i < 4; ++i) {
                        heapV[p][1 + (tn << 2) + i] = simv[i][j];
                        heapI[p][1 + (tn << 2) + i] = nbase + (tn << 2) + i;
                    }
                }
                pending = 0;
            }
            __syncthreads();
            if (t < PT) {     // heapify (sift-down roots 16..1)
                for (int rt = 16; rt >= 1; --rt) {
                    const float v = heapV[t][rt];
                    const int  ix = heapI[t][rt];
                    int i = rt;
                    while (true) {
                        const int l = i << 1;
                        if (l > 32) break;
                        int m = l;
                        float vm = heapV[t][l];
                        if (l + 1 <= 32) {
                            const float vr = heapV[t][l + 1];
                            if (vr < vm) { m = l + 1; vm = vr; }
                        }
                        if (vm >= v) break;
                        heapV[t][i] = vm; heapI[t][i] = heapI[t][m];
                        i = m;
                    }
                    heapV[t][i] = v; heapI[t][i] = ix;
                }
            }
            __syncthreads();
        }

        while (true) {
            if (t == 0) pendAny = 0;
            if (t < PT) qCnt[t] = 0;
            __syncthreads();
            if (pending) {
                #pragma unroll
                for (int j = 0; j < 4; ++j) {
                    const int p = (tp << 2) + j;
                    const float mv = heapV[p][1];
                    #pragma unroll
                    for (int i = 0; i < 4; ++i) {
                        const unsigned bitm = 1u << ((j << 2) + i);
                        if (pending & bitm) {
                            const float v = simv[i][j];
                            if (v > mv) {
                                const int slot = atomicAdd(&qCnt[p], 1);
                                if (slot < 32) {
                                    qV[p][slot] = v;
                                    qI[p][slot] = nstart + (tn << 2) + i;
                                    pending &= ~bitm;
                                }
                            } else pending &= ~bitm;
                        }
                    }
                }
                if (pending) pendAny = 1;
            }
            __syncthreads();
            if (t < PT) {
                int cnt = qCnt[t]; if (cnt > 32) cnt = 32;
                for (int s = 0; s < cnt; ++s) {
                    const float v = qV[t][s];
                    if (v > heapV[t][1]) {       // replace root + sift down
                        const int ix = qI[t][s];
                        int i = 1;
                        while (true) {
                            const int l = i << 1;
                            if (l > 32) break;
                            int m = l;
                            float vm = heapV[t][l];
                            if (l + 1 <= 32) {
                                const float vr = heapV[t][l + 1];
                                if (vr < vm) { m = l + 1; vm = vr; }
                            }
                            if (vm >= v) break;
                            heapV[t][i] = vm; heapI[t][i] = heapI[t][m];
                            i = m;
                        }
                        heapV[t][i] = v; heapI[t][i] = ix;
                    }
                }
            }
            __syncthreads();
            const int again = pendAny;
            __syncthreads();
            if (!again) break;
        }
    }

    // ---- write per-chunk top-32 candidates ----
    for (int idx = t; idx < PT * 32; idx += 256) {
        const int p = idx >> 5, s = idx & 31;
        const size_t gp = (size_t)b * HWP + p0 + p;
        partV[gp * NC + ns * 32 + s] = heapV[p][1 + s];
        partI[gp * NC + ns * 32 + s] = (float)heapI[p][1 + s];
    }
}

// ---------------------------------------------------------------------------
// Stage 2: merge NC=128 candidates -> exact top-30 softmax -> gather + blend.
// grid = BSZ * 64 blocks (16 px), 256 threads.
// ---------------------------------------------------------------------------
__global__ __launch_bounds__(256) void merge_kernel(
    const float* __restrict__ partV, const float* __restrict__ partI,
    const float* __restrict__ Vv, const float* __restrict__ lmv,
    const float* __restrict__ prelog, const float* __restrict__ W,
    float* __restrict__ out, int use_vt)
{
    __shared__ float candV[PT2][NC + 1];
    __shared__ int   candI[PT2][NC + 1];
    __shared__ float hV[PT2][34];
    __shared__ int   hI[PT2][34];
    __shared__ float probS[PT2][33];
    __shared__ int   selS[PT2][33];
    __shared__ float prelS[PT2];
    __shared__ float partS[4][PT2];
    __shared__ float upS[PT2];
    __shared__ float visS[CVC][PT2 + 1];

    const int t  = threadIdx.x;
    const int b  = blockIdx.x >> 6;
    const int pg = blockIdx.x & 63;
    const int p0 = pg << 4;

    for (int idx = t; idx < PT2 * NC; idx += 256) {
        const int p = idx >> 7, s = idx & (NC - 1);
        const size_t gp = (size_t)b * HWP + p0 + p;
        candV[p][s] = partV[gp * NC + s];
        candI[p][s] = (int)partI[gp * NC + s];
    }
    if (t < PT2) prelS[t] = prelog[b * HWP + p0 + t];
    __syncthreads();

    if (t < PT2) {
        const int p = t;
        // seed heap with first 32 candidates, heapify, stream the rest
        #pragma unroll
        for (int s = 0; s < 32; ++s) { hV[p][1 + s] = candV[p][s]; hI[p][1 + s] = candI[p][s]; }
        for (int rt = 16; rt >= 1; --rt) {
            const float v = hV[p][rt]; const int ix = hI[p][rt];
            int i = rt;
            while (true) {
                const int l = i << 1;
                if (l > 32) break;
                int m = l;
                float vm = hV[p][l];
                if (l + 1 <= 32) { const float vr = hV[p][l + 1]; if (vr < vm) { m = l + 1; vm = vr; } }
                if (vm >= v) break;
                hV[p][i] = vm; hI[p][i] = hI[p][m];
                i = m;
            }
            hV[p][i] = v; hI[p][i] = ix;
        }
        for (int s = 32; s < NC; ++s) {
            const float v = candV[p][s];
            if (v > hV[p][1]) {
                const int ix = candI[p][s];
                int i = 1;
                while (true) {
                    const int l = i << 1;
                    if (l > 32) break;
                    int m = l;
                    float vm = hV[p][l];
                    if (l + 1 <= 32) { const float vr = hV[p][l + 1]; if (vr < vm) { m = l + 1; vm = vr; } }
                    if (vm >= v) break;
                    hV[p][i] = vm; hI[p][i] = hI[p][m];
                    i = m;
                }
                hV[p][i] = v; hI[p][i] = ix;
            }
        }
        // 2 smallest of the 32: root, then min(child2, child3)
        const int m1 = 1;
        const int m2 = (hV[p][3] < hV[p][2]) ? 3 : 2;
        float mx = hV[p][1];
        #pragma unroll
        for (int s = 2; s <= 32; ++s) mx = fmaxf(mx, hV[p][s]);
        float sum = 0.f;
        #pragma unroll
        for (int s = 1; s <= 32; ++s) {
            const float e = (s == m1 || s == m2) ? 0.f : expf(hV[p][s] - mx);
            probS[p][s - 1] = e; sum += e;
            selS[p][s - 1]  = hI[p][s];
        }
        const float inv = 1.f / sum;
        #pragma unroll
        for (int s = 0; s < 32; ++s) probS[p][s] *= inv;
    }
    __syncthreads();

    // ---- gather visual (t = channel) + logit partial reduce ----
    const int c  = t;
    const int ln = t & 63;
    const int wv = t >> 6;
    float vis[PT2];
    const float* Vb = Vv + (use_vt ? (size_t)b * NMEM * CVC : (size_t)b * CVC * NMEM);
    #pragma unroll
    for (int p = 0; p < PT2; ++p) {
        float a = 0.f;
        for (int s = 0; s < 32; ++s) {
            const float pr = probS[p][s];           // wave-uniform broadcast
            if (pr != 0.f) {
                const int idx = selS[p][s];
                const float v = use_vt ? Vb[(size_t)idx * CVC + c]
                                       : Vb[(size_t)c * NMEM + idx];
                a = fmaf(pr, v, a);
            }
        }
        vis[p] = a;
        visS[c][p] = a;
    }
    const float w3 = W[513 + c];
    #pragma unroll
    for (int p = 0; p < PT2; ++p) {
        float v = w3 * vis[p];
        #pragma unroll
        for (int off = 32; off > 0; off >>= 1) v += __shfl_xor(v, off, 64);
        if (ln == 0) partS[wv][p] = v;
    }
    __syncthreads();
    if (t < PT2) {
        const float lg = prelS[t] + partS[0][t] + partS[1][t] + partS[2][t] + partS[3][t];
        upS[t] = 1.f / (1.f + expf(-lg));
    }
    __syncthreads();

    // ---- transposed, 64B-coalesced blend + store ----
    const int pp = t & 15;
    const int cg = t >> 4;
    const float u = upS[pp];
    #pragma unroll
    for (int ci = 0; ci < 16; ++ci) {
        const int cc = (cg << 4) + ci;
        const float vv = visS[cc][pp];
        const size_t off = ((size_t)b * CVC + cc) * HWP + p0 + pp;
        out[off] = vv * u + lmv[off] * (1.f - u);
    }
}

// ---------------------------------------------------------------------------
extern "C" void kernel_launch(void* const* d_in, const int* in_sizes, int n_in,
                              void* d_out, int out_size, void* d_ws, size_t ws_size,
                              hipStream_t stream)
{
    const float* qk  = (const float*)d_in[0];
    const float* qe  = (const float*)d_in[1];
    const float* pf  = (const float*)d_in[2];
    const float* lm  = (const float*)d_in[4];
    const float* lpf = (const float*)d_in[5];
    const float* lmv = (const float*)d_in[6];
    const float* mk  = (const float*)d_in[7];
    const float* shr = (const float*)d_in[8];
    const float* Vv  = (const float*)d_in[9];
    const float* vld = (const float*)d_in[10];
    const float* W   = (const float*)d_in[12];
    const float* bu  = (const float*)d_in[13];
    float* out = (float*)d_out;
    float* ws  = (float*)d_ws;

    float* Bq     = ws + WS_BQ_OFF;
    float* bsq    = ws + WS_BSQ_OFF;
    float* prelog = ws + WS_PRE_OFF;
    float* partV  = ws + WS_PARTV_OFF;
    float* partI  = ws + WS_PARTI_OFF;
    float* VT     = ws + WS_VT_OFF;
    const int use_vt = (ws_size >= (size_t)WS_TOTAL_FLOATS * sizeof(float)) ? 1 : 0;

    prep_kernel<<<BSZ * 64, 256, 0, stream>>>(qk, qe, pf, lm, lpf, lmv, W, bu,
                                              Bq, bsq, prelog);
    if (use_vt)
        transpose_v<<<dim3(NMEM / 32, CVC / 32, BSZ), dim3(32, 8), 0, stream>>>(Vv, VT);
    sim_topk_kernel<<<BSZ * 32 * NSPLIT, 256, 0, stream>>>(mk, shr, vld, Bq, bsq,
                                                           partV, partI);
    merge_kernel<<<BSZ * 64, 256, 0, stream>>>(partV, partI, use_vt ? VT : Vv,
                                               lmv, prelog, W, out, use_vt);
}

// Round 5
// 671.503 us; speedup vs baseline: 1.4027x; 1.1918x over previous
//
#include <hip/hip_runtime.h>
#include <math.h>

typedef __attribute__((ext_vector_type(8))) short bf16x8;   // 8 bf16 = 4 VGPR
typedef __attribute__((ext_vector_type(4))) float f32x4;

#define BSZ 4
#define CKC 64
#define HWP 1024
#define NMEM 16384
#define CVC 256

#define NSPLIT 8
#define CHUNK 2048          // NMEM/NSPLIT
#define NITER 16            // CHUNK/128
#define NC 256              // NSPLIT*32 merge candidates per pixel
#define PT 64               // pixels per sim block
#define QC 18               // candidate queue depth

// ---- workspace layout (floats). Essentials first; VT optional. ----
#define WS_APACK_OFF 0
#define WS_APACK_SZ  8388608        // 4b * 128nblk * 4ks * 16KB = 32MB
#define WS_BPACK_OFF (WS_APACK_OFF + WS_APACK_SZ)
#define WS_BPACK_SZ  524288         // 4b * 1024p * 512B = 2MB
#define WS_BQ_OFF    (WS_BPACK_OFF + WS_BPACK_SZ)
#define WS_BQ_SZ     (BSZ * 128 * HWP)
#define WS_BSQ_OFF   (WS_BQ_OFF + WS_BQ_SZ)
#define WS_BSQ_SZ    (BSZ * HWP)
#define WS_PRE_OFF   (WS_BSQ_OFF + WS_BSQ_SZ)
#define WS_PRE_SZ    (BSZ * HWP)
#define WS_PARTV_OFF (WS_PRE_OFF + WS_PRE_SZ)
#define WS_PARTV_SZ  (BSZ * HWP * NC)
#define WS_PARTI_OFF (WS_PARTV_OFF + WS_PARTV_SZ)
#define WS_PARTI_SZ  (BSZ * HWP * NC)
#define WS_SELP_OFF  (WS_PARTI_OFF + WS_PARTI_SZ)
#define WS_SELP_SZ   (BSZ * HWP * 32)
#define WS_SELI_OFF  (WS_SELP_OFF + WS_SELP_SZ)
#define WS_SELI_SZ   (BSZ * HWP * 32)
#define WS_VT_OFF    (WS_SELI_OFF + WS_SELI_SZ)
#define WS_VT_SZ     8388608        // 4b * 16384n * 256c bf16 = 32MB
#define WS_TOTAL_FLOATS (WS_VT_OFF + WS_VT_SZ)

// ---------------------------------------------------------------------------
// bf16 helpers (RNE)
// ---------------------------------------------------------------------------
__device__ __forceinline__ unsigned short f2bf(float x) {
    unsigned u = __float_as_uint(x);
    u = (u + 0x7FFFu + ((u >> 16) & 1u)) >> 16;
    return (unsigned short)u;
}
__device__ __forceinline__ float bfhi(float x) {   // bf16-rounded value of x, as float
    unsigned u = __float_as_uint(x);
    u = (u + 0x7FFFu + ((u >> 16) & 1u)) & 0xFFFF0000u;
    return __uint_as_float(u);
}

__device__ __forceinline__ void gld16(const void* g, void* l) {
    __builtin_amdgcn_global_load_lds(
        (const __attribute__((address_space(1))) unsigned int*)g,
        (__attribute__((address_space(3))) unsigned int*)l, 16, 0, 0);
}

#define BAR()  asm volatile("s_barrier" ::: "memory")
#define LBAR() asm volatile("s_waitcnt lgkmcnt(0)\n\ts_barrier" ::: "memory")
#define VM4()  asm volatile("s_waitcnt vmcnt(4)" ::: "memory")
#define VM0()  asm volatile("s_waitcnt vmcnt(0)" ::: "memory")

// ---------------------------------------------------------------------------
// Prep: Bq rows 0..63 = 2*qk*qe ("f"), rows 64..127 = -qe ("g");
// bsq[p] = sum_c qe*qk^2 ; prelogit[p] = b + W_lm*lm + W1.lpf + W2.pf - W3.lmv
// ---------------------------------------------------------------------------
__global__ __launch_bounds__(256) void prep_kernel(
    const float* __restrict__ qk, const float* __restrict__ qe,
    const float* __restrict__ pf, const float* __restrict__ lm,
    const float* __restrict__ lpf, const float* __restrict__ lmv,
    const float* __restrict__ W, const float* __restrict__ bu,
    float* __restrict__ Bq, float* __restrict__ bsq, float* __restrict__ prelog)
{
    __shared__ float red[16][17];
    const int t  = threadIdx.x;
    const int b  = blockIdx.x >> 6;
    const int p0 = (blockIdx.x & 63) << 4;
    const int pp = t & 15;
    const int cg = t >> 4;
    const int p  = p0 + pp;

    const float* qkb = qk + (size_t)b * CKC * HWP;
    const float* qeb = qe + (size_t)b * CKC * HWP;
    float* Bqb = Bq + (size_t)b * 128 * HWP;

    float bs = 0.f;
    #pragma unroll
    for (int i = 0; i < 4; ++i) {
        const int cidx = (cg << 2) + i;
        const float k_ = qkb[cidx * HWP + p];
        const float e_ = qeb[cidx * HWP + p];
        Bqb[cidx * HWP + p]        = 2.f * k_ * e_;
        Bqb[(64 + cidx) * HWP + p] = -e_;
        bs += e_ * k_ * k_;
    }
    red[cg][pp] = bs;
    __syncthreads();
    if (t < 16) {
        float s = 0.f;
        #pragma unroll
        for (int g2 = 0; g2 < 16; ++g2) s += red[g2][t];
        bsq[b * HWP + p0 + t] = s;
    }
    const float* lpfb = lpf + (size_t)b * CVC * HWP;
    const float* pfb  = pf  + (size_t)b * CVC * HWP;
    const float* lmvb = lmv + (size_t)b * CVC * HWP;
    float lg = 0.f;
    #pragma unroll
    for (int i = 0; i < 16; ++i) {
        const int cidx = (cg << 4) + i;
        lg += W[cidx]       * lpfb[cidx * HWP + p];
        lg += W[256 + cidx] * pfb[cidx * HWP + p];
        lg -= W[513 + cidx] * lmvb[cidx * HWP + p];
    }
    __syncthreads();
    red[cg][pp] = lg;
    __syncthreads();
    if (t < 16) {
        float s = bu[0] + W[512] * lm[b * HWP + p0 + t];
        #pragma unroll
        for (int g2 = 0; g2 < 16; ++g2) s += red[g2][t];
        prelog[b * HWP + p0 + t] = s;
    }
}

// ---------------------------------------------------------------------------
// pack_a: A = [mk ; mk^2] as hi/lo bf16, tiled (b, nblk, kstep) 16KB tiles,
// rows r = n&127 (128B: 4 c-octets x {hi,lo} 16B slots), slot XOR-swizzled
// by (r&7) so sim-kernel ds_read_b128 is conflict-free with a LINEAR
// global_load_lds destination (source pre-swizzle, T2/m201 pattern).
// ---------------------------------------------------------------------------
__global__ __launch_bounds__(256) void pack_a(const float* __restrict__ mk,
                                              unsigned int* __restrict__ Ap)
{
    __shared__ float ld[128][65];
    const int t = threadIdx.x;
    const int b = blockIdx.x >> 7;
    const int nblk = blockIdx.x & 127;
    const int n0 = nblk << 7;
    const float* mkb = mk + (size_t)b * CKC * NMEM;
    #pragma unroll
    for (int k = 0; k < 8; ++k) {
        const int i = t + (k << 8);          // 0..2047 float4s
        const int c = i >> 5;                // 0..63
        const int f4 = i & 31;               // 0..31
        const float4 v = *(const float4*)&mkb[(size_t)c * NMEM + n0 + (f4 << 2)];
        ld[(f4 << 2) + 0][c] = v.x; ld[(f4 << 2) + 1][c] = v.y;
        ld[(f4 << 2) + 2][c] = v.z; ld[(f4 << 2) + 3][c] = v.w;
    }
    __syncthreads();
    const int r = t >> 1;
    const int half = t & 1;
    #pragma unroll
    for (int kk = 0; kk < 2; ++kk) {
        const int ks = half * 2 + kk;
        const size_t tileByte = ((size_t)((b * 128 + nblk) * 4 + ks)) * 16384;
        #pragma unroll
        for (int g8 = 0; g8 < 4; ++g8) {
            unsigned hi[8], lo[8];
            #pragma unroll
            for (int j = 0; j < 8; ++j) {
                const int c = ks * 32 + g8 * 8 + j;
                const float base = (c < 64) ? ld[r][c] : ld[r][c - 64];
                const float x = (c < 64) ? base : base * base;
                const float h = bfhi(x);
                hi[j] = __float_as_uint(h) >> 16;
                lo[j] = (unsigned)f2bf(x - h);
            }
            uint4 hv, lv;
            hv.x = hi[0] | (hi[1] << 16); hv.y = hi[2] | (hi[3] << 16);
            hv.z = hi[4] | (hi[5] << 16); hv.w = hi[6] | (hi[7] << 16);
            lv.x = lo[0] | (lo[1] << 16); lv.y = lo[2] | (lo[3] << 16);
            lv.z = lo[4] | (lo[5] << 16); lv.w = lo[6] | (lo[7] << 16);
            const int sh = (g8 * 2 + 0) ^ (r & 7);
            const int sl = (g8 * 2 + 1) ^ (r & 7);
            *(uint4*)((char*)Ap + tileByte + r * 128 + sh * 16) = hv;
            *(uint4*)((char*)Ap + tileByte + r * 128 + sl * 16) = lv;
        }
    }
}

// ---------------------------------------------------------------------------
// pack_b: B = [f ; g] per pixel: Bpack[b][p][ks][g][h][8c] bf16 (512B / pixel)
// ---------------------------------------------------------------------------
__global__ __launch_bounds__(256) void pack_b(const float* __restrict__ Bq,
                                              unsigned int* __restrict__ Bp)
{
    const int tid = blockIdx.x * 256 + threadIdx.x;   // 0..65535
    const int o = tid & 15;
    const int p = (tid >> 4) & 1023;
    const int b = tid >> 14;
    const int ks = o >> 2, g = o & 3;
    const float* Bqb = Bq + (size_t)b * 128 * HWP;
    unsigned hi[8], lo[8];
    #pragma unroll
    for (int j = 0; j < 8; ++j) {
        const int c = ks * 32 + g * 8 + j;
        const float x = Bqb[(size_t)c * HWP + p];
        const float h = bfhi(x);
        hi[j] = __float_as_uint(h) >> 16;
        lo[j] = (unsigned)f2bf(x - h);
    }
    uint4 hv, lv;
    hv.x = hi[0] | (hi[1] << 16); hv.y = hi[2] | (hi[3] << 16);
    hv.z = hi[4] | (hi[5] << 16); hv.w = hi[6] | (hi[7] << 16);
    lv.x = lo[0] | (lo[1] << 16); lv.y = lo[2] | (lo[3] << 16);
    lv.z = lo[4] | (lo[5] << 16); lv.w = lo[6] | (lo[7] << 16);
    char* dst = (char*)Bp + ((size_t)(b * 1024 + p)) * 512 + ks * 128 + g * 32;
    *(uint4*)(dst)      = hv;
    *(uint4*)(dst + 16) = lv;
}

// ---------------------------------------------------------------------------
// Transpose mem_msk_value [b][c][n] -> VT [b][n][c] in bf16
// ---------------------------------------------------------------------------
__global__ __launch_bounds__(256) void transpose_v(const float* __restrict__ V,
                                                   unsigned short* __restrict__ VT)
{
    __shared__ float tile[32][33];
    const int b  = blockIdx.z;
    const int n0 = blockIdx.x << 5;
    const int c0 = blockIdx.y << 5;
    const int tx = threadIdx.x, ty = threadIdx.y;  // 32 x 8
    const float* Vb = V + (size_t)b * CVC * NMEM;
    unsigned short* VTb = VT + (size_t)b * NMEM * CVC;
    #pragma unroll
    for (int i = 0; i < 32; i += 8)
        tile[ty + i][tx] = Vb[(size_t)(c0 + ty + i) * NMEM + n0 + tx];
    __syncthreads();
    #pragma unroll
    for (int i = 0; i < 32; i += 8)
        VTb[(size_t)(n0 + ty + i) * CVC + c0 + tx] = f2bf(tile[tx][ty + i]);
}

// ---------------------------------------------------------------------------
// sim_mfma: split-bf16 MFMA sim GEMM (128n x 64p block tile, 4 waves each
// 64n x 32p) fused with streaming per-pixel top-32 heaps.
// grid = 512 blocks (b x 16pg x 8ns, XCD-chunk-swizzled), 256 threads.
// ---------------------------------------------------------------------------
__global__ __launch_bounds__(256) void sim_mfma(
    const unsigned int* __restrict__ Ap, const unsigned int* __restrict__ Bp,
    const float* __restrict__ shr, const float* __restrict__ valid,
    const float* __restrict__ bsq,
    float* __restrict__ partV, float* __restrict__ partI)
{
    __shared__ bf16x8 Abuf[2][1024];       // 2 x 16KB double buffer
    __shared__ float2 shrpenS[CHUNK];      // (shr*0.125, pen) for the chunk
    __shared__ float  bsqS[64];
    __shared__ float  heapV[64][33];       // 1-indexed min-heaps
    __shared__ int    heapI[64][33];
    __shared__ float  qV[64][QC];
    __shared__ int    qI[64][QC];
    __shared__ int    qCnt[64];
    __shared__ int    pendAny;

    const int t = threadIdx.x;
    const int bid = blockIdx.x;
    const int wk = ((bid & 7) << 6) + (bid >> 3);   // XCD-chunked swizzle (512%8==0)
    const int pg = wk & 15;
    const int ns = (wk >> 4) & 7;
    const int b  = wk >> 7;
    const int p0 = pg << 6;
    const int w  = t >> 6;
    const int l  = t & 63;
    const int wn = w >> 1;        // n-half of block tile
    const int wp = w & 1;         // p-half
    const int col = l & 15;
    const int g   = l >> 4;

    {   // chunk-resident scalars
        const float* shrb = shr   + (size_t)b * NMEM + ns * CHUNK;
        const float* vlb  = valid + (size_t)b * NMEM + ns * CHUNK;
        #pragma unroll
        for (int k = 0; k < 8; ++k) {
            const int i = t + (k << 8);
            shrpenS[i] = make_float2(shrb[i] * 0.125f, (1.f - vlb[i]) * -60000.f);
        }
        if (t < 64) { bsqS[t] = bsq[(size_t)b * HWP + p0 + t]; qCnt[t] = 0; }
        if (t == 0) pendAny = 0;
    }

    // B fragments -> registers (hi/lo, 4 ksteps, 2 p-tiles) = 64 VGPR
    bf16x8 Bf[2][4][2];
    {
        const char* BpB = (const char*)Bp;
        #pragma unroll
        for (int tj = 0; tj < 2; ++tj) {
            const int p = p0 + wp * 32 + tj * 16 + col;
            const char* base = BpB + ((size_t)(b * 1024 + p)) * 512 + g * 32;
            #pragma unroll
            for (int ks = 0; ks < 4; ++ks) {
                Bf[tj][ks][0] = *(const bf16x8*)(base + ks * 128);
                Bf[tj][ks][1] = *(const bf16x8*)(base + ks * 128 + 16);
            }
        }
    }
    __syncthreads();              // full drain: staging + B loads complete
    const float bq[2] = { bsqS[wp * 32 + col], bsqS[wp * 32 + 16 + col] };

    const char* ApB = (const char*)Ap + ((size_t)((b * 128 + ns * 16) * 4)) * 16384;
    char* AbB = (char*)&Abuf[0][0];

    #define STAGE(seqq) do {                                                   \
        const char* gsrc_ = ApB + (size_t)(seqq) * 16384 + w * 4096 + l * 16;  \
        char* ldst_ = AbB + (((seqq) & 1) << 14) + w * 4096;                   \
        gld16(gsrc_,        ldst_);                                            \
        gld16(gsrc_ + 1024, ldst_ + 1024);                                     \
        gld16(gsrc_ + 2048, ldst_ + 2048);                                     \
        gld16(gsrc_ + 3072, ldst_ + 3072);                                     \
    } while (0)

    STAGE(0);

    for (int iter = 0; iter < NITER; ++iter) {
        f32x4 acc[4][2];
        #pragma unroll
        for (int ti = 0; ti < 4; ++ti) {
            acc[ti][0] = (f32x4){0.f, 0.f, 0.f, 0.f};
            acc[ti][1] = (f32x4){0.f, 0.f, 0.f, 0.f};
        }

        #pragma unroll
        for (int ks = 0; ks < 4; ++ks) {
            const int seq = iter * 4 + ks;
            BAR();                                   // prev compute done everywhere
            if (seq < 63) { STAGE(seq + 1); VM4(); } // keep next tile in flight
            else          { VM0(); }
            BAR();                                   // current tile resident
            const bf16x8* Ab = &Abuf[0][0] + ((seq & 1) << 10);
            #pragma unroll
            for (int ti = 0; ti < 4; ++ti) {
                const int r = wn * 64 + ti * 16 + col;
                const bf16x8 aH = Ab[r * 8 + (((g << 1)    ) ^ (col & 7))];
                const bf16x8 aL = Ab[r * 8 + (((g << 1) + 1) ^ (col & 7))];
                #pragma unroll
                for (int tj = 0; tj < 2; ++tj) {
                    acc[ti][tj] = __builtin_amdgcn_mfma_f32_16x16x32_bf16(aH, Bf[tj][ks][0], acc[ti][tj], 0, 0, 0);
                    acc[ti][tj] = __builtin_amdgcn_mfma_f32_16x16x32_bf16(aH, Bf[tj][ks][1], acc[ti][tj], 0, 0, 0);
                    acc[ti][tj] = __builtin_amdgcn_mfma_f32_16x16x32_bf16(aL, Bf[tj][ks][0], acc[ti][tj], 0, 0, 0);
                }
            }
        }

        // ---- scale: sim = (acc - bsq)*shr + pen ----
        float simr[4][2][4];
        #pragma unroll
        for (int ti = 0; ti < 4; ++ti) {
            #pragma unroll
            for (int rr = 0; rr < 4; ++rr) {
                const int nl = wn * 64 + ti * 16 + (g << 2) + rr;
                const float2 sp = shrpenS[iter * 128 + nl];
                #pragma unroll
                for (int tj = 0; tj < 2; ++tj)
                    simr[ti][tj][rr] = fmaf(acc[ti][tj][rr] - bq[tj], sp.x, sp.y);
            }
        }

        // ---- streaming top-32 ----
        unsigned pend = 0xFFFFFFFFu;      // bit = ti*8 + tj*4 + rr
        if (iter == 0) {
            if (wn == 0) {                // seed heap slots 1..32 with n 0..31
                #pragma unroll
                for (int ti = 0; ti < 2; ++ti)
                    #pragma unroll
                    for (int tj = 0; tj < 2; ++tj) {
                        const int pl = wp * 32 + tj * 16 + col;
                        #pragma unroll
                        for (int rr = 0; rr < 4; ++rr) {
                            const int slot = ti * 16 + (g << 2) + rr + 1;
                            heapV[pl][slot] = simr[ti][tj][rr];
                            heapI[pl][slot] = ns * CHUNK + ti * 16 + (g << 2) + rr;
                        }
                    }
                pend = 0xFFFF0000u;
            }
            LBAR();
            if (t < 64) {                 // heapify
                for (int rt = 16; rt >= 1; --rt) {
                    const float v = heapV[t][rt]; const int ix = heapI[t][rt];
                    int i = rt;
                    while (true) {
                        const int lc = i << 1;
                        if (lc > 32) break;
                        int m = lc; float vm = heapV[t][lc];
                        if (lc + 1 <= 32) { const float vr = heapV[t][lc + 1]; if (vr < vm) { m = lc + 1; vm = vr; } }
                        if (vm >= v) break;
                        heapV[t][i] = vm; heapI[t][i] = heapI[t][m];
                        i = m;
                    }
                    heapV[t][i] = v; heapI[t][i] = ix;
                }
            }
            LBAR();
        }

        while (true) {
            if (t == 0) pendAny = 0;
            if (t < 64) qCnt[t] = 0;
            LBAR();
            if (pend) {
                #pragma unroll
                for (int tj = 0; tj < 2; ++tj) {
                    const int pl = wp * 32 + tj * 16 + col;
                    const float root = heapV[pl][1];
                    #pragma unroll
                    for (int ti = 0; ti < 4; ++ti) {
                        #pragma unroll
                        for (int rr = 0; rr < 4; ++rr) {
                            const unsigned bitm = 1u << (ti * 8 + tj * 4 + rr);
                            if (pend & bitm) {
                                const float v = simr[ti][tj][rr];
                                if (v > root) {
                                    const int s = atomicAdd(&qCnt[pl], 1);
                                    if (s < QC) {
                                        qV[pl][s] = v;
                                        qI[pl][s] = ns * CHUNK + iter * 128 + wn * 64 + ti * 16 + (g << 2) + rr;
                                        pend &= ~bitm;
                                    }
                                } else pend &= ~bitm;
                            }
                        }
                    }
                }
                if (pend) pendAny = 1;
            }
            LBAR();
            if (t < 64) {
                int cnt = qCnt[t]; if (cnt > QC) cnt = QC;
                for (int s = 0; s < cnt; ++s) {
                    const float v = qV[t][s];
                    if (v > heapV[t][1]) {
                        const int ix = qI[t][s];
                        int i = 1;
                        while (true) {
                            const int lc = i << 1;
                            if (lc > 32) break;
                            int m = lc; float vm = heapV[t][lc];
                            if (lc + 1 <= 32) { const float vr = heapV[t][lc + 1]; if (vr < vm) { m = lc + 1; vm = vr; } }
                            if (vm >= v) break;
                            heapV[t][i] = vm; heapI[t][i] = heapI[t][m];
                            i = m;
                        }
                        heapV[t][i] = v; heapI[t][i] = ix;
                    }
                }
            }
            LBAR();
            const int again = pendAny;
            LBAR();
            if (!again) break;
        }
    }

    // ---- write per-chunk top-32 candidates ----
    for (int idx = t; idx < 64 * 32; idx += 256) {
        const int p = idx >> 5, s = idx & 31;
        const size_t gp = (size_t)b * HWP + p0 + p;
        partV[gp * NC + ns * 32 + s] = heapV[p][1 + s];
        partI[gp * NC + ns * 32 + s] = (float)heapI[p][1 + s];
    }
    #undef STAGE
}

// ---------------------------------------------------------------------------
// merge_select: exact top-32 of NC=256 candidates, softmax over top-30,
// write (prob, idx) records. grid = BSZ*64 (16 px), 256 threads.
// ---------------------------------------------------------------------------
__global__ __launch_bounds__(256) void merge_select(
    const float* __restrict__ partV, const float* __restrict__ partI,
    float* __restrict__ selP, int* __restrict__ selI)
{
    __shared__ float candV[16][NC + 1];
    __shared__ int   candI[16][NC + 1];
    __shared__ float hV[16][34];
    __shared__ int   hI[16][34];
    __shared__ float probS[16][33];
    __shared__ int   selS[16][33];

    const int t  = threadIdx.x;
    const int b  = blockIdx.x >> 6;
    const int pg = blockIdx.x & 63;
    const int p0 = pg << 4;

    for (int idx = t; idx < 16 * NC; idx += 256) {
        const int p = idx >> 8, s = idx & (NC - 1);
        const size_t gp = (size_t)b * HWP + p0 + p;
        candV[p][s] = partV[gp * NC + s];
        candI[p][s] = (int)partI[gp * NC + s];
    }
    __syncthreads();

    if (t < 16) {
        const int p = t;
        #pragma unroll
        for (int s = 0; s < 32; ++s) { hV[p][1 + s] = candV[p][s]; hI[p][1 + s] = candI[p][s]; }
        for (int rt = 16; rt >= 1; --rt) {
            const float v = hV[p][rt]; const int ix = hI[p][rt];
            int i = rt;
            while (true) {
                const int lc = i << 1;
                if (lc > 32) break;
                int m = lc; float vm = hV[p][lc];
                if (lc + 1 <= 32) { const float vr = hV[p][lc + 1]; if (vr < vm) { m = lc + 1; vm = vr; } }
                if (vm >= v) break;
                hV[p][i] = vm; hI[p][i] = hI[p][m];
                i = m;
            }
            hV[p][i] = v; hI[p][i] = ix;
        }
        for (int s = 32; s < NC; ++s) {
            const float v = candV[p][s];
            if (v > hV[p][1]) {
                const int ix = candI[p][s];
                int i = 1;
                while (true) {
                    const int lc = i << 1;
                    if (lc > 32) break;
                    int m = lc; float vm = hV[p][lc];
                    if (lc + 1 <= 32) { const float vr = hV[p][lc + 1]; if (vr < vm) { m = lc + 1; vm = vr; } }
                    if (vm >= v) break;
                    hV[p][i] = vm; hI[p][i] = hI[p][m];
                    i = m;
                }
                hV[p][i] = v; hI[p][i] = ix;
            }
        }
        const int m1 = 1;
        const int m2 = (hV[p][3] < hV[p][2]) ? 3 : 2;
        float mx = hV[p][1];
        #pragma unroll
        for (int s = 2; s <= 32; ++s) mx = fmaxf(mx, hV[p][s]);
        float sum = 0.f;
        #pragma unroll
        for (int s = 1; s <= 32; ++s) {
            const float e = (s == m1 || s == m2) ? 0.f : expf(hV[p][s] - mx);
            probS[p][s - 1] = e; sum += e;
            selS[p][s - 1]  = hI[p][s];
        }
        const float inv = 1.f / sum;
        #pragma unroll
        for (int s = 0; s < 32; ++s) probS[p][s] *= inv;
    }
    __syncthreads();

    for (int idx = t; idx < 512; idx += 256) {
        const int p = idx >> 5, s = idx & 31;
        const size_t gp = (size_t)b * HWP + p0 + p;
        selP[gp * 32 + s] = probS[p][s];
        selI[gp * 32 + s] = selS[p][s];
    }
}

// ---------------------------------------------------------------------------
// gather_blend: visual = sum_s prob*V[idx] (coalesced bf16-VT rows), then
// uncertainty-gated blend + transposed coalesced store.
// grid = BSZ*64 (16 px), 256 threads (t = channel).
// ---------------------------------------------------------------------------
__global__ __launch_bounds__(256) void gather_blend(
    const float* __restrict__ selP, const int* __restrict__ selI,
    const unsigned short* __restrict__ VT, const float* __restrict__ Vv,
    const float* __restrict__ lmv, const float* __restrict__ prelog,
    const float* __restrict__ W, float* __restrict__ out, int use_vt)
{
    __shared__ float probS[16][33];
    __shared__ int   selS[16][33];
    __shared__ float prelS[16];
    __shared__ float partS[4][16];
    __shared__ float upS[16];
    __shared__ float visS[CVC][17];

    const int t  = threadIdx.x;
    const int b  = blockIdx.x >> 6;
    const int pg = blockIdx.x & 63;
    const int p0 = pg << 4;

    for (int idx = t; idx < 512; idx += 256) {
        const int p = idx >> 5, s = idx & 31;
        const size_t gp = (size_t)b * HWP + p0 + p;
        probS[p][s] = selP[gp * 32 + s];
        selS[p][s]  = selI[gp * 32 + s];
    }
    if (t < 16) prelS[t] = prelog[b * HWP + p0 + t];
    __syncthreads();

    const int c  = t;
    const int ln = t & 63;
    const int wv = t >> 6;
    float vis[16];
    const unsigned short* VTb = VT + (size_t)b * NMEM * CVC;
    const float* Vb = Vv + (size_t)b * CVC * NMEM;
    #pragma unroll
    for (int p = 0; p < 16; ++p) {
        float a = 0.f;
        for (int s = 0; s < 32; ++s) {
            const float pr = probS[p][s];
            if (pr != 0.f) {
                const int idx = selS[p][s];
                float v;
                if (use_vt) v = __uint_as_float(((unsigned)VTb[(size_t)idx * CVC + c]) << 16);
                else        v = Vb[(size_t)c * NMEM + idx];
                a = fmaf(pr, v, a);
            }
        }
        vis[p] = a;
        visS[c][p] = a;
    }
    const float w3 = W[513 + c];
    #pragma unroll
    for (int p = 0; p < 16; ++p) {
        float v = w3 * vis[p];
        #pragma unroll
        for (int off = 32; off > 0; off >>= 1) v += __shfl_xor(v, off, 64);
        if (ln == 0) partS[wv][p] = v;
    }
    __syncthreads();
    if (t < 16) {
        const float lg = prelS[t] + partS[0][t] + partS[1][t] + partS[2][t] + partS[3][t];
        upS[t] = 1.f / (1.f + expf(-lg));
    }
    __syncthreads();
    const int pp = t & 15;
    const int cg = t >> 4;
    const float u = upS[pp];
    #pragma unroll
    for (int ci = 0; ci < 16; ++ci) {
        const int cc = (cg << 4) + ci;
        const float vv = visS[cc][pp];
        const size_t off = ((size_t)b * CVC + cc) * HWP + p0 + pp;
        out[off] = vv * u + lmv[off] * (1.f - u);
    }
}

// ---------------------------------------------------------------------------
extern "C" void kernel_launch(void* const* d_in, const int* in_sizes, int n_in,
                              void* d_out, int out_size, void* d_ws, size_t ws_size,
                              hipStream_t stream)
{
    const float* qk  = (const float*)d_in[0];
    const float* qe  = (const float*)d_in[1];
    const float* pf  = (const float*)d_in[2];
    const float* lm  = (const float*)d_in[4];
    const float* lpf = (const float*)d_in[5];
    const float* lmv = (const float*)d_in[6];
    const float* mk  = (const float*)d_in[7];
    const float* shr = (const float*)d_in[8];
    const float* Vv  = (const float*)d_in[9];
    const float* vld = (const float*)d_in[10];
    const float* W   = (const float*)d_in[12];
    const float* bu  = (const float*)d_in[13];
    float* out = (float*)d_out;
    float* ws  = (float*)d_ws;

    unsigned int* Apack = (unsigned int*)(ws + WS_APACK_OFF);
    unsigned int* Bpack = (unsigned int*)(ws + WS_BPACK_OFF);
    float* Bq     = ws + WS_BQ_OFF;
    float* bsq    = ws + WS_BSQ_OFF;
    float* prelog = ws + WS_PRE_OFF;
    float* partV  = ws + WS_PARTV_OFF;
    float* partI  = ws + WS_PARTI_OFF;
    float* selP   = ws + WS_SELP_OFF;
    int*   selI   = (int*)(ws + WS_SELI_OFF);
    unsigned short* VT = (unsigned short*)(ws + WS_VT_OFF);
    const int use_vt = (ws_size >= (size_t)WS_TOTAL_FLOATS * sizeof(float)) ? 1 : 0;

    prep_kernel<<<BSZ * 64, 256, 0, stream>>>(qk, qe, pf, lm, lpf, lmv, W, bu,
                                              Bq, bsq, prelog);
    pack_a<<<BSZ * 128, 256, 0, stream>>>(mk, Apack);
    pack_b<<<256, 256, 0, stream>>>(Bq, Bpack);
    if (use_vt)
        transpose_v<<<dim3(NMEM / 32, CVC / 32, BSZ), dim3(32, 8), 0, stream>>>(Vv, VT);
    sim_mfma<<<512, 256, 0, stream>>>(Apack, Bpack, shr, vld, bsq, partV, partI);
    merge_select<<<BSZ * 64, 256, 0, stream>>>(partV, partI, selP, selI);
    gather_blend<<<BSZ * 64, 256, 0, stream>>>(selP, selI, VT, Vv, lmv, prelog,
                                               W, out, use_vt);
}